// Round 4
// baseline (235.738 us; speedup 1.0000x reference)
//
#include <hip/hip_runtime.h>
#include <math.h>

#define CIN   128
#define COUT  128
#define KKT   9
#define NSTAT 32768.0f   // B*H*W per-channel count

typedef __attribute__((ext_vector_type(8))) short bf16x8;
typedef __attribute__((ext_vector_type(4))) float f32x4;
typedef __attribute__((ext_vector_type(2))) float f32x2;

__device__ inline unsigned short f2bf(float f) {
    union { float f; unsigned u; } v; v.f = f;
    unsigned r = v.u + 0x7fffu + ((v.u >> 16) & 1u);
    return (unsigned short)(r >> 16);
}
// unpack bf16 c-pair dword -> float2 {even-ch, odd-ch}
__device__ inline f32x2 bf2(unsigned u) {
    union { unsigned u; float f; } lo, hi;
    lo.u = u << 16; hi.u = u & 0xffff0000u;
    f32x2 r; r[0] = lo.f; r[1] = hi.f; return r;
}
// bilinear blend of one c-pair dword from 4 corners -> packed bf16 pair
__device__ inline unsigned blend1(unsigned c00, unsigned c01, unsigned c10, unsigned c11,
                                  float w00, float w01, float w10, float w11) {
    f32x2 s = bf2(c00) * w00;
    s += bf2(c01) * w01;
    s += bf2(c10) * w10;
    s += bf2(c11) * w11;
    unsigned pk;
    asm("v_cvt_pk_bf16_f32 %0, %1, %2" : "=v"(pk) : "v"(s[0]), "v"(s[1]));
    return pk;
}

// ---------------- ws layout (bytes) ----------------
// xt  : 16777216   bf16 channel-last x[b][y][x][c], stored as dword c-pairs
// wb  : 294912     [oc][kt*128+c] bf16   (main conv A)
// wob : 73728      [32 ocpad][kt*128+c] bf16 (offset conv A, rows 18..31 zero)
// sums: 512 | sumsq

// Fused: blocks 0..511 transpose x -> xt; blocks 512.. repack weights + zero stats
__global__ __launch_bounds__(512) void prep_all_k(const float* __restrict__ x,
                                                  unsigned* __restrict__ xt,
                                                  const float* __restrict__ w_def,
                                                  const float* __restrict__ w_off,
                                                  unsigned short* __restrict__ wb,
                                                  unsigned short* __restrict__ wob,
                                                  float* __restrict__ sums) {
    __shared__ float lt[128][65];
    const int bb = blockIdx.x;
    if (bb < 512) {
        const int b = bb >> 6, y = bb & 63;
        const int t = threadIdx.x, l = t & 63, g8 = t >> 6;   // g8: 0..7
        const float* xb = x + (b * 128) * 4096 + y * 64;
#pragma unroll
        for (int pass = 0; pass < 16; pass++) {
            int c = pass * 8 + g8;
            lt[c][l] = xb[c * 4096 + l];
        }
        __syncthreads();
        unsigned* xo = xt + (bb * 64) * 64;   // pixel base (dwords)
#pragma unroll
        for (int pass = 0; pass < 8; pass++) {
            int w = pass * 8 + g8;
            float f0 = lt[2 * l][w], f1 = lt[2 * l + 1][w];
            xo[w * 64 + l] = (unsigned)f2bf(f0) | ((unsigned)f2bf(f1) << 16);
        }
    } else {
        int i = (bb - 512) * 512 + threadIdx.x;
        if (i < 147456) {
            int oc = i / 1152, r = i - oc * 1152, kt = r >> 7, c = r & 127;
            wb[i] = f2bf(w_def[(oc * 128 + c) * 9 + kt]);
        } else if (i < 147456 + 36864) {
            int j = i - 147456;
            int ocp = j / 1152, r = j - ocp * 1152, kt = r >> 7, c = r & 127;
            wob[j] = (ocp < 18) ? f2bf(w_off[(ocp * 128 + c) * 9 + kt]) : (unsigned short)0;
        } else if (i < 147456 + 36864 + 256) {
            sums[i - 147456 - 36864] = 0.f;   // sums|sumsq zero (re-poisoned each launch)
        }
    }
}

// One block per (b,h), XCD-swizzled. 512 threads = 8 waves.
// LDS 51712 B: xrow[0,50688) (prologue only); tab[0,18432) + offl[18432,23040)
// alias it after xrow is dead; stat[50688,51712).
// Main tap loop is BARRIER-FREE: each lane gathers its own MFMA-B fragment bytes
// from the 4 bilinear corners and blends in registers (lane = pixel(lo) x c-octet(quad)).
__global__ __launch_bounds__(512, 4) void deform_main_k(const unsigned* __restrict__ xt,
                                                        const unsigned short* __restrict__ wb,
                                                        const unsigned short* __restrict__ wob,
                                                        const float* __restrict__ b_def,
                                                        float* __restrict__ out,
                                                        float* __restrict__ sums,
                                                        float* __restrict__ sumsq) {
    __shared__ __align__(16) unsigned char smem[51712];
    unsigned short* xrow = (unsigned short*)smem;            // [3][66][128] bf16, 50688 B
    int*            tab  = (int*)smem;                       // [9*64][8] dwords, 18432 B
    float* offl = (float*)(smem + 18432);                    // [18][64]
    float* stat = (float*)(smem + 50688);                    // [256]

    const int t    = threadIdx.x;
    const int bh   = blockIdx.x;
    const int b    = bh >> 6;
    const int j_   = bh & 63;
    const int h    = ((j_ & 7) << 3) | (j_ >> 3);   // XCD-locality swizzle
    const int lane = t & 63;
    const int wv   = __builtin_amdgcn_readfirstlane(t >> 6);  // 0..7
    const int quad = lane >> 4, lo = lane & 15;
    const int l    = lane;        // c-pair index for staging loads
    const int g    = lane >> 2;   // c-octet index 0..15

    const unsigned* xtb = xt + b * 262144;   // dwords per batch image

    // ---- stage xrow: rows h-1..h+1, x = -1..64, zero-padded, swizzled ----
#pragma unroll
    for (int it = 0; it < 25; it++) {
        int p = wv + it * 8;
        if (p < 198) {
            int r = p / 66, xi = p - r * 66;
            int y = h + r - 1, x = xi - 1;
            unsigned u = 0;
            if ((unsigned)y < 64u && (unsigned)x < 64u) u = xtb[(y * 64 + x) * 64 + l];
            ((unsigned*)xrow)[(r * 66 + xi) * 64 + ((g ^ (xi & 15)) << 2) + (l & 3)] = u;
        }
    }
    __syncthreads();

    // ---- offset conv via MFMA: wave -> (mt = wv>>2, nt = wv&3), D[oc][w] ----
    {
        const int omt = wv >> 2, ont = wv & 3;
        f32x4 ao = {0.f, 0.f, 0.f, 0.f};
        const unsigned short* wrow = wob + (omt * 16 + lo) * 1152 + quad * 8;
        for (int kt = 0; kt < 9; kt++) {
            int ky = kt / 3, kx = kt - ky * 3;
            int xi = ont * 16 + lo + kx;   // xrow x-index = w + kx
#pragma unroll
            for (int ch = 0; ch < 4; ch++) {
                int gg = ch * 4 + quad;
                bf16x8 af = *(const bf16x8*)(wrow + kt * 128 + ch * 32);
                bf16x8 bf = *(const bf16x8*)(xrow + (ky * 66 + xi) * 128 + ((gg ^ (xi & 15)) << 3));
                ao = __builtin_amdgcn_mfma_f32_16x16x32_bf16(af, bf, ao, 0, 0, 0);
            }
        }
        __syncthreads();   // all waves done reading xrow
#pragma unroll
        for (int r = 0; r < 4; r++) {
            int oc = omt * 16 + quad * 4 + r;
            if (oc < 18) offl[oc * 64 + ont * 16 + lo] = ao[r];
        }
    }
    __syncthreads();   // offl ready; xrow region free for tab

    // ---- tap tables: 4 corner pixel bases (uint4 units) + 4 COMBINED weights ----
    for (int i = t; i < KKT * 64; i += 512) {
        int k = i >> 6, w2i = i & 63;
        float dy = offl[(2 * k) * 64 + w2i];
        float dx = offl[(2 * k + 1) * 64 + w2i];
        int ky = k / 3, kx = k - ky * 3;
        float ys = (float)(h - 1 + ky) + dy;
        float xs = (float)(w2i - 1 + kx) + dx;
        float y0f = floorf(ys), x0f = floorf(xs);
        float wyf = ys - y0f, wxf = xs - x0f;
        int iy0 = (int)y0f, ix0 = (int)x0f;
        int cy0 = min(max(iy0, 0), 63), cy1 = min(max(iy0 + 1, 0), 63);
        int px  = min(max(ix0, 0), 63), px2 = min(max(ix0 + 1, 0), 63);
        float wy0 = (iy0 >= 0 && iy0 < 64) ? (1.f - wyf) : 0.f;
        float wy1 = (iy0 + 1 >= 0 && iy0 + 1 < 64) ? wyf : 0.f;
        float wa  = (ix0 >= 0 && ix0 < 64) ? (1.f - wxf) : 0.f;
        float wbv = (ix0 + 1 >= 0 && ix0 + 1 < 64) ? wxf : 0.f;
        int base = i * 8;
        tab[base + 0] = (cy0 * 64 + px ) * 16;   // uint4 units (pixel row = 256B)
        tab[base + 1] = (cy0 * 64 + px2) * 16;
        tab[base + 2] = (cy1 * 64 + px ) * 16;
        tab[base + 3] = (cy1 * 64 + px2) * 16;
        ((float*)tab)[base + 4] = wy0 * wa;   // w00
        ((float*)tab)[base + 5] = wy0 * wbv;  // w01
        ((float*)tab)[base + 6] = wy1 * wa;   // w10
        ((float*)tab)[base + 7] = wy1 * wbv;  // w11
    }
    if (t < 256) stat[t] = 0.f;
    __syncthreads();

    // ---- main tap loop: barrier-free, in-register B-fragment gather+blend ----
    // wave -> (nt = wv&3 pixel tile, oh = wv>>2 oc half); lane -> pixel lo, c-octet quad
    const int nt = wv & 3, oh = wv >> 2;
    const int w2 = nt * 16 + lo;             // this lane's pixel column
    const uint4* xt4 = (const uint4*)xtb;
    const unsigned short* abase = wb + (oh * 64 + lo) * 1152 + quad * 8;

    f32x4 acc[4];
#pragma unroll
    for (int a = 0; a < 4; a++)
#pragma unroll
        for (int r = 0; r < 4; r++) acc[a][r] = 0.f;

    // prefetched per-lane tap data (addresses + combined weights)
    int4   cb = *(const int4*)&tab[w2 * 8];
    float4 tw = *(const float4*)&tab[w2 * 8 + 4];

    for (int kt = 0; kt < KKT; kt++) {
        int ktn = (kt + 1 < KKT) ? kt + 1 : kt;
        int4   cbn = *(const int4*)&tab[(ktn * 64 + w2) * 8];
        float4 twn = *(const float4*)&tab[(ktn * 64 + w2) * 8 + 4];
#pragma unroll
        for (int ch = 0; ch < 4; ch++) {
            const int co = ch * 4 + quad;                 // uint4 offset inside pixel
            uint4 c00 = xt4[cb.x + co];
            uint4 c01 = xt4[cb.y + co];
            uint4 c10 = xt4[cb.z + co];
            uint4 c11 = xt4[cb.w + co];
            const unsigned short* ap = abase + kt * 128 + ch * 32;
            bf16x8 a0 = *(const bf16x8*)(ap);
            bf16x8 a1 = *(const bf16x8*)(ap + 18432);     // +16 oc rows (16*1152)
            bf16x8 a2 = *(const bf16x8*)(ap + 36864);
            bf16x8 a3 = *(const bf16x8*)(ap + 55296);
            uint4 bq;
            bq.x = blend1(c00.x, c01.x, c10.x, c11.x, tw.x, tw.y, tw.z, tw.w);
            bq.y = blend1(c00.y, c01.y, c10.y, c11.y, tw.x, tw.y, tw.z, tw.w);
            bq.z = blend1(c00.z, c01.z, c10.z, c11.z, tw.x, tw.y, tw.z, tw.w);
            bq.w = blend1(c00.w, c01.w, c10.w, c11.w, tw.x, tw.y, tw.z, tw.w);
            bf16x8 bfv = *(bf16x8*)&bq;
            acc[0] = __builtin_amdgcn_mfma_f32_16x16x32_bf16(a0, bfv, acc[0], 0, 0, 0);
            acc[1] = __builtin_amdgcn_mfma_f32_16x16x32_bf16(a1, bfv, acc[1], 0, 0, 0);
            acc[2] = __builtin_amdgcn_mfma_f32_16x16x32_bf16(a2, bfv, acc[2], 0, 0, 0);
            acc[3] = __builtin_amdgcn_mfma_f32_16x16x32_bf16(a3, bfv, acc[3], 0, 0, 0);
        }
        cb = cbn; tw = twn;
    }

    // ---- epilogue: bias + store + fused BN stats ----
    float* ob = out + b * COUT * 4096 + h * 64;
#pragma unroll
    for (int a = 0; a < 4; a++) {
#pragma unroll
        for (int r = 0; r < 4; r++) {
            int oc = (oh * 4 + a) * 16 + quad * 4 + r;
            float v = acc[a][r] + b_def[oc];
            ob[oc * 4096 + w2] = v;
            float ssum = v, qsum = v * v;
#pragma unroll
            for (int d = 1; d < 16; d <<= 1) {
                ssum += __shfl_xor(ssum, d, 64);
                qsum += __shfl_xor(qsum, d, 64);
            }
            if (lo == 0) { atomicAdd(&stat[oc], ssum); atomicAdd(&stat[128 + oc], qsum); }
        }
    }
    __syncthreads();
    if (t < 256) {
        float* gp = (t < 128) ? (sums + t) : (sumsq + (t - 128));
        atomicAdd(gp, stat[t]);
    }
}

__global__ __launch_bounds__(256) void bn_silu_k(float* __restrict__ out,
                                                 const float* __restrict__ sums,
                                                 const float* __restrict__ sumsq,
                                                 const float* __restrict__ gamma,
                                                 const float* __restrict__ beta) {
    __shared__ float sc_s[128], sh_s[128];
    int t = threadIdx.x;
    if (t < 128) {
        const float invN = 1.f / NSTAT;
        float m = sums[t] * invN;
        float v = fmaf(-m, m, sumsq[t] * invN);
        float sc = gamma[t] * rsqrtf(v + 1e-5f);
        sc_s[t] = sc;
        sh_s[t] = beta[t] - m * sc;
    }
    __syncthreads();
    int i = blockIdx.x * 256 + t;
    float4 v = ((float4*)out)[i];
    int oc = (i >> 10) & 127;
    float sc = sc_s[oc], sh = sh_s[oc];
    float z0 = v.x * sc + sh;
    float z1 = v.y * sc + sh;
    float z2 = v.z * sc + sh;
    float z3 = v.w * sc + sh;
    v.x = z0 / (1.f + __expf(-z0));
    v.y = z1 / (1.f + __expf(-z1));
    v.z = z2 / (1.f + __expf(-z2));
    v.w = z3 / (1.f + __expf(-z3));
    ((float4*)out)[i] = v;
}

extern "C" void kernel_launch(void* const* d_in, const int* in_sizes, int n_in,
                              void* d_out, int out_size, void* d_ws, size_t ws_size,
                              hipStream_t stream) {
    const float* x     = (const float*)d_in[0];
    const float* w_off = (const float*)d_in[1];
    const float* w_def = (const float*)d_in[2];
    const float* b_def = (const float*)d_in[3];
    const float* gamma = (const float*)d_in[4];
    const float* beta  = (const float*)d_in[5];
    float* out = (float*)d_out;

    unsigned*       xt   = (unsigned*)d_ws;                               // 16777216 B
    unsigned short* wb   = (unsigned short*)((char*)d_ws + 16777216);     // 294912 B
    unsigned short* wob  = (unsigned short*)((char*)d_ws + 17072128);     // 73728 B
    float*          sums = (float*)((char*)d_ws + 17145856);              // 128
    float*          sumsq = sums + 128;

    prep_all_k<<<873, 512, 0, stream>>>(x, xt, w_def, w_off, wb, wob, sums);
    deform_main_k<<<512, 512, 0, stream>>>(xt, wb, wob, b_def, out, sums, sumsq);
    bn_silu_k<<<4096, 256, 0, stream>>>(out, sums, sumsq, gamma, beta);
}

// Round 5
// 197.340 us; speedup vs baseline: 1.1946x; 1.1946x over previous
//
#include <hip/hip_runtime.h>
#include <math.h>

#define CIN   128
#define COUT  128
#define KKT   9
#define NSTAT 32768.0f   // B*H*W per-channel count

typedef __attribute__((ext_vector_type(8))) short bf16x8;
typedef __attribute__((ext_vector_type(4))) float f32x4;
typedef __attribute__((ext_vector_type(2))) float f32x2;

__device__ inline unsigned short f2bf(float f) {
    union { float f; unsigned u; } v; v.f = f;
    unsigned r = v.u + 0x7fffu + ((v.u >> 16) & 1u);
    return (unsigned short)(r >> 16);
}
// unpack bf16 c-pair dword -> float2 {even-ch, odd-ch}
__device__ inline f32x2 bf2(unsigned u) {
    union { unsigned u; float f; } lo, hi;
    lo.u = u << 16; hi.u = u & 0xffff0000u;
    f32x2 r; r[0] = lo.f; r[1] = hi.f; return r;
}

// publish LDS writes, then barrier — does NOT drain vmcnt (prefetch loads stay in flight)
#define PUB_BARRIER() do { asm volatile("s_waitcnt lgkmcnt(0)" ::: "memory"); \
                           __builtin_amdgcn_s_barrier(); } while (0)

// ---------------- ws layout (bytes) ----------------
// xt  : 16777216   bf16 channel-last x[b][y][x][c], stored as dword c-pairs
// wb  : 294912     [oc][kt*128+c] bf16   (main conv A)
// wob : 73728      [32 ocpad][kt*128+c] bf16 (offset conv A, rows 18..31 zero)
// sums: 512 | sumsq

// Fused: blocks 0..511 transpose x -> xt; blocks 512.. repack weights + zero stats
__global__ __launch_bounds__(512) void prep_all_k(const float* __restrict__ x,
                                                  unsigned* __restrict__ xt,
                                                  const float* __restrict__ w_def,
                                                  const float* __restrict__ w_off,
                                                  unsigned short* __restrict__ wb,
                                                  unsigned short* __restrict__ wob,
                                                  float* __restrict__ sums) {
    __shared__ float lt[128][65];
    const int bb = blockIdx.x;
    if (bb < 512) {
        const int b = bb >> 6, y = bb & 63;
        const int t = threadIdx.x, l = t & 63, g8 = t >> 6;   // g8: 0..7
        const float* xb = x + (b * 128) * 4096 + y * 64;
#pragma unroll
        for (int pass = 0; pass < 16; pass++) {
            int c = pass * 8 + g8;
            lt[c][l] = xb[c * 4096 + l];
        }
        __syncthreads();
        unsigned* xo = xt + (bb * 64) * 64;   // pixel base (dwords)
#pragma unroll
        for (int pass = 0; pass < 8; pass++) {
            int w = pass * 8 + g8;
            float f0 = lt[2 * l][w], f1 = lt[2 * l + 1][w];
            xo[w * 64 + l] = (unsigned)f2bf(f0) | ((unsigned)f2bf(f1) << 16);
        }
    } else {
        int i = (bb - 512) * 512 + threadIdx.x;
        if (i < 147456) {
            int oc = i / 1152, r = i - oc * 1152, kt = r >> 7, c = r & 127;
            wb[i] = f2bf(w_def[(oc * 128 + c) * 9 + kt]);
        } else if (i < 147456 + 36864) {
            int j = i - 147456;
            int ocp = j / 1152, r = j - ocp * 1152, kt = r >> 7, c = r & 127;
            wob[j] = (ocp < 18) ? f2bf(w_off[(ocp * 128 + c) * 9 + kt]) : (unsigned short)0;
        } else if (i < 147456 + 36864 + 256) {
            sums[i - 147456 - 36864] = 0.f;   // sums|sumsq zero (re-poisoned each launch)
        }
    }
}

// One block per (b,h), XCD-swizzled. 1024 threads = 16 waves, 2 blocks/CU.
// PRODUCER/CONSUMER: waves 0..7 gather+blend tap kt+1 into samp[(kt+1)&1] while
// waves 8..15 run MFMA on samp[kt&1] with register-double-buffered A-fragments.
// Stalls decorrelate: producer vmem waits overlap consumer MFMA/ds_read.
// LDS 56832 B: xrow[0,50688) (prologue; tab[0,18432)+samp0[18432,34816)+
// samp1[34816,51200) alias it); offl[51200,55808); stat[55808,56832).
__global__ __launch_bounds__(1024, 8) void deform_main_k(const unsigned* __restrict__ xt,
                                                         const unsigned short* __restrict__ wb,
                                                         const unsigned short* __restrict__ wob,
                                                         const float* __restrict__ b_def,
                                                         float* __restrict__ out,
                                                         float* __restrict__ sums,
                                                         float* __restrict__ sumsq) {
    __shared__ __align__(16) unsigned char smem[56832];
    unsigned short* xrow  = (unsigned short*)smem;             // [3][66][128] bf16, 50688 B
    int*            tab   = (int*)smem;                        // [9*64][8] dwords, 18432 B
    unsigned short* samp0 = (unsigned short*)(smem + 18432);   // [64][128] bf16
    unsigned short* samp1 = (unsigned short*)(smem + 34816);
    float* offl = (float*)(smem + 51200);                      // [18][64]
    float* stat = (float*)(smem + 55808);                      // [256]

    const int t    = threadIdx.x;
    const int bh   = blockIdx.x;
    const int b    = bh >> 6;
    const int j_   = bh & 63;
    const int h    = ((j_ & 7) << 3) | (j_ >> 3);   // XCD-locality swizzle
    const int lane = t & 63;
    const int wv   = __builtin_amdgcn_readfirstlane(t >> 6);  // 0..15
    const int quad = lane >> 4, lo = lane & 15;
    const int l    = lane;        // c-pair index for gathers
    const int g    = lane >> 2;   // c-octet index 0..15

    if (t < 256) stat[t] = 0.f;

    const unsigned* xtb = xt + b * 262144;   // dwords per batch image

    // ---- stage xrow: rows h-1..h+1, x = -1..64, zero-padded, swizzled ----
#pragma unroll
    for (int it = 0; it < 13; it++) {
        int p = wv + it * 16;
        if (p < 198) {
            int r = p / 66, xi = p - r * 66;
            int y = h + r - 1, x = xi - 1;
            unsigned u = 0;
            if ((unsigned)y < 64u && (unsigned)x < 64u) u = xtb[(y * 64 + x) * 64 + l];
            ((unsigned*)xrow)[(r * 66 + xi) * 64 + ((g ^ (xi & 15)) << 2) + (l & 3)] = u;
        }
    }
    __syncthreads();

    // ---- offset conv via MFMA (waves 0..7): wave -> (mt = wv>>2, nt = wv&3) ----
    {
        const int omt = wv >> 2, ont = wv & 3;
        f32x4 ao = {0.f, 0.f, 0.f, 0.f};
        if (wv < 8) {
            const unsigned short* wrow = wob + (omt * 16 + lo) * 1152 + quad * 8;
            for (int kt = 0; kt < 9; kt++) {
                int ky = kt / 3, kx = kt - ky * 3;
                int xi = ont * 16 + lo + kx;   // xrow x-index = w + kx
#pragma unroll
                for (int ch = 0; ch < 4; ch++) {
                    int gg = ch * 4 + quad;
                    bf16x8 af = *(const bf16x8*)(wrow + kt * 128 + ch * 32);
                    bf16x8 bf = *(const bf16x8*)(xrow + (ky * 66 + xi) * 128 + ((gg ^ (xi & 15)) << 3));
                    ao = __builtin_amdgcn_mfma_f32_16x16x32_bf16(af, bf, ao, 0, 0, 0);
                }
            }
        }
        __syncthreads();   // all waves done reading xrow
        if (wv < 8) {
#pragma unroll
            for (int r = 0; r < 4; r++) {
                int oc = omt * 16 + quad * 4 + r;
                if (oc < 18) offl[oc * 64 + ont * 16 + lo] = ao[r];
            }
        }
    }
    __syncthreads();   // offl ready; xrow region free for tab

    // ---- tap tables: 4 corner pixel bases (dword units) + 4 COMBINED weights ----
    for (int i = t; i < KKT * 64; i += 1024) {
        int k = i >> 6, w2i = i & 63;
        float dy = offl[(2 * k) * 64 + w2i];
        float dx = offl[(2 * k + 1) * 64 + w2i];
        int ky = k / 3, kx = k - ky * 3;
        float ys = (float)(h - 1 + ky) + dy;
        float xs = (float)(w2i - 1 + kx) + dx;
        float y0f = floorf(ys), x0f = floorf(xs);
        float wyf = ys - y0f, wxf = xs - x0f;
        int iy0 = (int)y0f, ix0 = (int)x0f;
        int cy0 = min(max(iy0, 0), 63), cy1 = min(max(iy0 + 1, 0), 63);
        int px  = min(max(ix0, 0), 63), px2 = min(max(ix0 + 1, 0), 63);
        float wy0 = (iy0 >= 0 && iy0 < 64) ? (1.f - wyf) : 0.f;
        float wy1 = (iy0 + 1 >= 0 && iy0 + 1 < 64) ? wyf : 0.f;
        float wa  = (ix0 >= 0 && ix0 < 64) ? (1.f - wxf) : 0.f;
        float wbv = (ix0 + 1 >= 0 && ix0 + 1 < 64) ? wxf : 0.f;
        int base = i * 8;
        tab[base + 0] = (cy0 * 64 + px ) * 64;   // dword units (pixel row = 64 dwords)
        tab[base + 1] = (cy0 * 64 + px2) * 64;
        tab[base + 2] = (cy1 * 64 + px ) * 64;
        tab[base + 3] = (cy1 * 64 + px2) * 64;
        ((float*)tab)[base + 4] = wy0 * wa;   // w00
        ((float*)tab)[base + 5] = wy0 * wbv;  // w01
        ((float*)tab)[base + 6] = wy1 * wa;   // w10
        ((float*)tab)[base + 7] = wy1 * wbv;  // w11
    }
    __syncthreads();

    // ---- main tap loop: producer/consumer wave specialization ----
    const bool prod = (wv < 8);
    const int  ot   = wv - 8;                  // consumer oc-tile 0..7
    const int  w0p  = wv << 3;                 // producer pixel base (8 pixels)

    // producer state: staged gather dwords (statically indexed)
    unsigned u0[8], u1[8], u2[8], u3[8];
    // consumer state: acc over 4 pixel-tiles; A-frag double buffer
    f32x4 acc[4];
    bf16x8 afc[4];
    const unsigned short* abase = wb + ((ot < 0 ? 0 : ot) * 16 + lo) * 1152 + quad * 8;

#pragma unroll
    for (int n = 0; n < 4; n++)
#pragma unroll
        for (int r = 0; r < 4; r++) acc[n][r] = 0.f;

    // produce(k): gather 8 pixels' 4 corners -> blend -> samp[k&1]
    auto produce = [&](int k) {
#pragma unroll
        for (int i = 0; i < 8; i++) {
            int w = w0p + i;
            const int4 a = *(const int4*)&tab[(k * 64 + w) * 8];   // broadcast LDS
            u0[i] = xtb[a.x + l]; u1[i] = xtb[a.y + l];
            u2[i] = xtb[a.z + l]; u3[i] = xtb[a.w + l];
        }
        unsigned* sb = (unsigned*)((k & 1) ? samp1 : samp0);
#pragma unroll
        for (int i = 0; i < 8; i++) {
            int w = w0p + i;
            const float4 tw = *(const float4*)&tab[(k * 64 + w) * 8 + 4];
            f32x2 s = bf2(u0[i]) * tw.x;
            s += bf2(u1[i]) * tw.y;
            s += bf2(u2[i]) * tw.z;
            s += bf2(u3[i]) * tw.w;
            unsigned pk;
            asm("v_cvt_pk_bf16_f32 %0, %1, %2" : "=v"(pk) : "v"(s[0]), "v"(s[1]));
            sb[w * 64 + ((g ^ (w & 15)) << 2) + (l & 3)] = pk;
        }
    };

    if (prod) {
        produce(0);
    } else {
#pragma unroll
        for (int ch = 0; ch < 4; ch++)
            afc[ch] = *(const bf16x8*)(abase + ch * 32);   // tap-0 A-frags
    }
    PUB_BARRIER();

    for (int kt = 0; kt < KKT; kt++) {
        if (prod) {
            if (kt < KKT - 1) produce(kt + 1);
        } else {
            // prefetch next tap's A-frags (stay in flight across MFMA)
            int ktn = (kt < KKT - 1) ? kt + 1 : kt;
            bf16x8 afn[4];
#pragma unroll
            for (int ch = 0; ch < 4; ch++)
                afn[ch] = *(const bf16x8*)(abase + ktn * 128 + ch * 32);
            const unsigned short* sbs = (kt & 1) ? samp1 : samp0;
#pragma unroll
            for (int ch = 0; ch < 4; ch++) {
                int gg = ch * 4 + quad;
#pragma unroll
                for (int n = 0; n < 4; n++) {
                    bf16x8 bfv = *(const bf16x8*)(sbs + (n * 16 + lo) * 128 + ((gg ^ lo) << 3));
                    acc[n] = __builtin_amdgcn_mfma_f32_16x16x32_bf16(afc[ch], bfv, acc[n], 0, 0, 0);
                }
            }
#pragma unroll
            for (int ch = 0; ch < 4; ch++) afc[ch] = afn[ch];
        }
        PUB_BARRIER();
    }

    // ---- epilogue (consumers): bias + store + fused BN stats ----
    if (!prod) {
        float* ob = out + b * COUT * 4096 + h * 64;
#pragma unroll
        for (int r = 0; r < 4; r++) {
            int oc = ot * 16 + quad * 4 + r;
            float bia = b_def[oc];
            float ssum = 0.f, qsum = 0.f;
#pragma unroll
            for (int n = 0; n < 4; n++) {
                float v = acc[n][r] + bia;
                ob[oc * 4096 + n * 16 + lo] = v;
                ssum += v; qsum += v * v;
            }
#pragma unroll
            for (int d = 1; d < 16; d <<= 1) {
                ssum += __shfl_xor(ssum, d, 64);
                qsum += __shfl_xor(qsum, d, 64);
            }
            if (lo == 0) { atomicAdd(&stat[oc], ssum); atomicAdd(&stat[128 + oc], qsum); }
        }
    }
    __syncthreads();
    if (t < 256) {
        float* gp = (t < 128) ? (sums + t) : (sumsq + (t - 128));
        atomicAdd(gp, stat[t]);
    }
}

__global__ __launch_bounds__(256) void bn_silu_k(float* __restrict__ out,
                                                 const float* __restrict__ sums,
                                                 const float* __restrict__ sumsq,
                                                 const float* __restrict__ gamma,
                                                 const float* __restrict__ beta) {
    __shared__ float sc_s[128], sh_s[128];
    int t = threadIdx.x;
    if (t < 128) {
        const float invN = 1.f / NSTAT;
        float m = sums[t] * invN;
        float v = fmaf(-m, m, sumsq[t] * invN);
        float sc = gamma[t] * rsqrtf(v + 1e-5f);
        sc_s[t] = sc;
        sh_s[t] = beta[t] - m * sc;
    }
    __syncthreads();
    int i = blockIdx.x * 256 + t;
    float4 v = ((float4*)out)[i];
    int oc = (i >> 10) & 127;
    float sc = sc_s[oc], sh = sh_s[oc];
    float z0 = v.x * sc + sh;
    float z1 = v.y * sc + sh;
    float z2 = v.z * sc + sh;
    float z3 = v.w * sc + sh;
    v.x = z0 / (1.f + __expf(-z0));
    v.y = z1 / (1.f + __expf(-z1));
    v.z = z2 / (1.f + __expf(-z2));
    v.w = z3 / (1.f + __expf(-z3));
    ((float4*)out)[i] = v;
}

extern "C" void kernel_launch(void* const* d_in, const int* in_sizes, int n_in,
                              void* d_out, int out_size, void* d_ws, size_t ws_size,
                              hipStream_t stream) {
    const float* x     = (const float*)d_in[0];
    const float* w_off = (const float*)d_in[1];
    const float* w_def = (const float*)d_in[2];
    const float* b_def = (const float*)d_in[3];
    const float* gamma = (const float*)d_in[4];
    const float* beta  = (const float*)d_in[5];
    float* out = (float*)d_out;

    unsigned*       xt   = (unsigned*)d_ws;                               // 16777216 B
    unsigned short* wb   = (unsigned short*)((char*)d_ws + 16777216);     // 294912 B
    unsigned short* wob  = (unsigned short*)((char*)d_ws + 17072128);     // 73728 B
    float*          sums = (float*)((char*)d_ws + 17145856);              // 128
    float*          sumsq = sums + 128;

    prep_all_k<<<873, 512, 0, stream>>>(x, xt, w_def, w_off, wb, wob, sums);
    deform_main_k<<<512, 1024, 0, stream>>>(xt, wb, wob, b_def, out, sums, sumsq);
    bn_silu_k<<<4096, 256, 0, stream>>>(out, sums, sumsq, gamma, beta);
}